// Round 2
// baseline (801.996 us; speedup 1.0000x reference)
//
#include <hip/hip_runtime.h>
#include <math.h>

// EarthAttention3D constants
#define B_   96
#define NW   10
#define NN   144
#define CC   192
#define HH   6
#define DH   32
#define SCALE 0.17677669529663687f  // 1/sqrt(32)

#define XP 200   // xs pitch (bf16): 400 B rows
#define PP 152   // Ps pitch: 304 B rows (12-bank row stride -> <=2-way, free)
#define NPASS 3
#define BWCHUNK 320          // 960 / NPASS
#define QKV_STRIDE (NN * DH) // 4608 elems per (h,s) matrix

typedef __attribute__((ext_vector_type(8))) short v8s;            // 8 x bf16
typedef __attribute__((ext_vector_type(4))) unsigned short v4us;  // 4 x bf16
typedef __attribute__((ext_vector_type(4))) float v4f;            // MFMA acc

__device__ __forceinline__ unsigned short f2b(float f) {  // fp32 -> bf16 RNE
  union { float f; unsigned u; } v; v.f = f;
  unsigned r = v.u + 0x7fffu + ((v.u >> 16) & 1u);
  return (unsigned short)(r >> 16);
}
__device__ __forceinline__ float b2f(unsigned short s) {
  union { unsigned u; float f; } v; v.u = ((unsigned)s) << 16;
  return v.f;
}

#define N_WQT (576*192)
#define N_WPT (192*192)
#define N_BIAS (NW*HH*NN*NN)

// ---------------------------------------------------------------------------
// Prep: wqT = w_qkv^T bf16, wpT = w_proj^T bf16, biasNN gathered bf16.
// ---------------------------------------------------------------------------
__global__ __launch_bounds__(256) void prep_kernel(
    const float* __restrict__ w_qkv, const float* __restrict__ w_proj,
    const float* __restrict__ bias_table, const int* __restrict__ pos,
    unsigned short* __restrict__ wqT, unsigned short* __restrict__ wpT,
    unsigned short* __restrict__ biasNN)
{
  int i = blockIdx.x * 256 + threadIdx.x;
  if (i < N_WQT) {
    int n = i / 192, k = i % 192;
    wqT[i] = f2b(w_qkv[k * 576 + n]);
  } else if (i < N_WQT + N_WPT) {
    int j = i - N_WQT;
    int n = j / 192, k = j % 192;
    wpT[j] = f2b(w_proj[k * 192 + n]);
  } else if (i < N_WQT + N_WPT + N_BIAS) {
    int j = i - (N_WQT + N_WPT);
    int m = j % NN, n = (j / NN) % NN, h = (j / (NN * NN)) % HH, w = j / (NN * NN * HH);
    biasNN[j] = f2b(bias_table[(pos[n * NN + m] * NW + w) * HH + h]);
  }
}

// ---------------------------------------------------------------------------
// QKV GEMM: block = (bw, 48-row third). 256 thr / 4 waves, 19.2 KB LDS.
// A-fragments hoisted to registers (reused across all 9 col-strips per wave).
// Output layout: q,k: [n][d];  v: TRANSPOSED [d][n] (packed 8B stores) so the
// attention kernel needs no LDS transpose at all.
// ---------------------------------------------------------------------------
__global__ __launch_bounds__(256, 3) void qkv_gemm(
    const float* __restrict__ x, const float* __restrict__ b_qkv,
    const unsigned short* __restrict__ wqT,
    unsigned short* __restrict__ qkv, int bw0)
{
  __shared__ unsigned short xs[48 * XP];   // 19,200 B
  const int tid  = threadIdx.x;
  const int wave = tid >> 6, lane = tid & 63;
  const int lr = lane & 15, lk8 = (lane >> 4) * 8, quad = lane >> 4;
  const int bwl = blockIdx.x / 3;
  const int rt3 = blockIdx.x % 3;
  const int bw  = bw0 + bwl;

  // stage 48 rows of x as bf16
  const float4* xp4 = (const float4*)(x + ((size_t)bw * NN + rt3 * 48) * CC);
  for (int i = tid; i < 48 * (CC / 4); i += 256) {
    float4 f = xp4[i];
    int r = i / (CC / 4), c = (i % (CC / 4)) * 4;
    unsigned short* d = &xs[r * XP + c];
    d[0] = f2b(f.x); d[1] = f2b(f.y); d[2] = f2b(f.z); d[3] = f2b(f.w);
  }
  __syncthreads();

  // hoist A-fragments: 3 row-tiles x 6 k-steps = 18 v8s (72 VGPRs)
  v8s a[3][6];
  #pragma unroll
  for (int ii = 0; ii < 3; ii++)
    #pragma unroll
    for (int ks = 0; ks < 6; ks++)
      a[ii][ks] = *(const v8s*)&xs[(ii * 16 + lr) * XP + ks * 32 + lk8];

  for (int c = wave; c < 36; c += 4) {      // 9 col-strips per wave
    const int s = c / 12;
    const int h = (c % 12) >> 1;
    const int dhalf = c & 1;
    const unsigned short* wrow = wqT + (size_t)(c * 16 + lr) * CC;
    v8s bf[6];
    #pragma unroll
    for (int ks = 0; ks < 6; ks++) bf[ks] = *(const v8s*)&wrow[ks * 32 + lk8];
    const float bv = b_qkv[c * 16 + lr];
    v4f acc[3];
    #pragma unroll
    for (int ii = 0; ii < 3; ii++) acc[ii] = (v4f){bv, bv, bv, bv};
    #pragma unroll
    for (int ks = 0; ks < 6; ks++)
      #pragma unroll
      for (int ii = 0; ii < 3; ii++)
        acc[ii] = __builtin_amdgcn_mfma_f32_16x16x32_bf16(a[ii][ks], bf[ks], acc[ii], 0, 0, 0);

    if (s == 2) {
      // V: store transposed [d][n], d = c-strip output channel, 4 n packed/8B
      unsigned short* opT = qkv + ((size_t)(bwl * HH + h) * 3 + 2) * QKV_STRIDE
                          + (size_t)(dhalf * 16 + lr) * NN;
      #pragma unroll
      for (int ii = 0; ii < 3; ii++) {
        const int n0 = rt3 * 48 + ii * 16 + quad * 4;
        v4us pk;
        #pragma unroll
        for (int r = 0; r < 4; r++) pk[r] = f2b(acc[ii][r]);
        *(v4us*)&opT[n0] = pk;
      }
    } else {
      unsigned short* op = qkv + ((size_t)(bwl * HH + h) * 3 + s) * QKV_STRIDE + dhalf * 16 + lr;
      #pragma unroll
      for (int ii = 0; ii < 3; ii++)
        #pragma unroll
        for (int r = 0; r < 4; r++) {
          const int n = rt3 * 48 + ii * 16 + quad * 4 + r;
          op[n * DH] = f2b(acc[ii][r]);
        }
    }
  }
}

// ---------------------------------------------------------------------------
// Attention per (b,w,h): 256 thr / 4 waves, 43.8 KB LDS -> 3 blocks/CU.
// q,k,vT read directly from global (L1-hot, 9 KB each). 2 barriers total.
// K=144 handled by register-masked tail MFMA (no zero-padded columns).
// Softmax: one 16-lane group per row, P normalized in place.
// ---------------------------------------------------------------------------
__global__ __launch_bounds__(256, 3) void attn_bwh(
    const unsigned short* __restrict__ qkv, const float* __restrict__ mask,
    const unsigned short* __restrict__ biasNN,
    unsigned short* __restrict__ ao, int bw0)
{
  __shared__ unsigned short Ps[NN * PP];   // 43,776 B

  const int tid  = threadIdx.x;
  const int wave = tid >> 6, lane = tid & 63;
  const int lr = lane & 15, lk8 = (lane >> 4) * 8, quad = lane >> 4;

  const int bwl = blockIdx.x / HH;
  const int h   = blockIdx.x % HH;
  const int bw  = bw0 + bwl;
  const int b   = bw / NW;
  const int w   = bw % NW;

  const unsigned short* qp = qkv + (size_t)(bwl * HH + h) * 3 * QKV_STRIDE;
  const unsigned short* kp = qp + QKV_STRIDE;
  const unsigned short* vT = qp + 2 * QKV_STRIDE;   // [32][144] transposed

  // ---- phase B: S = scale*q k^T + bias + mask -> bf16 logits in Ps --------
  // Q fragments hoisted: identical for every mt-strip this wave handles.
  v8s aq[9];
  #pragma unroll
  for (int nt = 0; nt < 9; nt++)
    aq[nt] = *(const v8s*)&qp[(nt * 16 + lr) * DH + lk8];

  const unsigned short* bp = biasNN + (size_t)(w * HH + h) * NN * NN;
  const float* mp = mask + (size_t)b * NN * NN;
  for (int mt = wave; mt < 9; mt += 4) {
    v8s bk = *(const v8s*)&kp[(mt * 16 + lr) * DH + lk8];
    const int m = mt * 16 + lr;
    #pragma unroll
    for (int nt = 0; nt < 9; nt++) {
      v4f c = {0.f, 0.f, 0.f, 0.f};
      c = __builtin_amdgcn_mfma_f32_16x16x32_bf16(aq[nt], bk, c, 0, 0, 0);
      #pragma unroll
      for (int r = 0; r < 4; r++) {
        const int n = nt * 16 + quad * 4 + r;
        float v = c[r] * SCALE + b2f(bp[n * NN + m]) + mp[n * NN + m];
        Ps[n * PP + m] = f2b(v);
      }
    }
  }
  __syncthreads();

  // ---- softmax: one 16-lane group per row (4 rows in flight per wave) -----
  for (int rr = 0; rr < 9; rr++) {
    const int row = rr * 16 + wave * 4 + quad;
    unsigned short* prow = &Ps[row * PP];
    float e[9];
    float mx = -1e30f;
    #pragma unroll
    for (int j = 0; j < 9; j++) {
      e[j] = b2f(prow[j * 16 + lr]);
      mx = fmaxf(mx, e[j]);
    }
    #pragma unroll
    for (int off = 8; off; off >>= 1) mx = fmaxf(mx, __shfl_xor(mx, off, 64));
    float s = 0.f;
    #pragma unroll
    for (int j = 0; j < 9; j++) { e[j] = __expf(e[j] - mx); s += e[j]; }
    #pragma unroll
    for (int off = 8; off; off >>= 1) s += __shfl_xor(s, off, 64);
    const float inv = 1.f / s;
    #pragma unroll
    for (int j = 0; j < 9; j++) prow[j * 16 + lr] = f2b(e[j] * inv);
  }
  __syncthreads();

  // ---- phase D: O = P @ v; V^T fragments hoisted from global --------------
  v8s bv[2][4], bvt[2];
  #pragma unroll
  for (int dh2 = 0; dh2 < 2; dh2++) {
    const unsigned short* vrow = vT + (size_t)(dh2 * 16 + lr) * NN;
    #pragma unroll
    for (int ks = 0; ks < 4; ks++) bv[dh2][ks] = *(const v8s*)&vrow[ks * 32 + lk8];
    bvt[dh2] = *(const v8s*)&vrow[128 + (lk8 & 8)];  // quads 2,3 read valid data, A-side is zeroed
  }
  const v8s vzero = {};
  for (int nt = wave; nt < 9; nt += 4) {
    v8s ap[4];
    #pragma unroll
    for (int ks = 0; ks < 4; ks++)
      ap[ks] = *(const v8s*)&Ps[(nt * 16 + lr) * PP + ks * 32 + lk8];
    v8s at = *(const v8s*)&Ps[(nt * 16 + lr) * PP + 128 + (lk8 & 8)];
    at = (quad < 2) ? at : vzero;   // k = 144..159 contributes zero
    #pragma unroll
    for (int dh2 = 0; dh2 < 2; dh2++) {
      v4f c = {0.f, 0.f, 0.f, 0.f};
      #pragma unroll
      for (int ks = 0; ks < 4; ks++)
        c = __builtin_amdgcn_mfma_f32_16x16x32_bf16(ap[ks], bv[dh2][ks], c, 0, 0, 0);
      c = __builtin_amdgcn_mfma_f32_16x16x32_bf16(at, bvt[dh2], c, 0, 0, 0);
      #pragma unroll
      for (int r = 0; r < 4; r++) {
        const int n = nt * 16 + quad * 4 + r;
        ao[((size_t)bw * NN + n) * CC + h * DH + dh2 * 16 + lr] = f2b(c[r]);
      }
    }
  }
}

// ---------------------------------------------------------------------------
// Proj: out = ao(bf16) @ w_proj + b_proj. 64 rows/block.
// ---------------------------------------------------------------------------
__global__ __launch_bounds__(256) void proj_mfma(
    const unsigned short* __restrict__ ao,
    const unsigned short* __restrict__ wpT,
    const float* __restrict__ b_proj,
    float* __restrict__ out)
{
  __shared__ unsigned short As[64 * XP];   // 25,600 B
  const int tid  = threadIdx.x;
  const int wave = tid >> 6, lane = tid & 63;
  const int lr = lane & 15, lk8 = (lane >> 4) * 8, quad = lane >> 4;
  const size_t row0 = (size_t)blockIdx.x * 64;

  for (int i = tid; i < 64 * 24; i += 256) {
    const int r = i / 24, c = i % 24;
    *(v8s*)&As[r * XP + c * 8] = *(const v8s*)(ao + (row0 + r) * CC + c * 8);
  }
  __syncthreads();

  v4f acc[12];
  #pragma unroll
  for (int j = 0; j < 12; j++) {
    const float bv = b_proj[j * 16 + lr];
    acc[j] = (v4f){bv, bv, bv, bv};
  }
  #pragma unroll
  for (int ks = 0; ks < 6; ks++) {
    const int k0 = ks * 32;
    v8s a = *(const v8s*)&As[(wave * 16 + lr) * XP + k0 + lk8];
    #pragma unroll
    for (int j = 0; j < 12; j++) {
      v8s bf = *(const v8s*)(wpT + (j * 16 + lr) * CC + k0 + lk8);
      acc[j] = __builtin_amdgcn_mfma_f32_16x16x32_bf16(a, bf, acc[j], 0, 0, 0);
    }
  }
  #pragma unroll
  for (int j = 0; j < 12; j++)
    #pragma unroll
    for (int r = 0; r < 4; r++)
      out[(row0 + wave * 16 + quad * 4 + r) * CC + j * 16 + lr] = acc[j][r];
}

// ---------------------------------------------------------------------------
extern "C" void kernel_launch(void* const* d_in, const int* in_sizes, int n_in,
                              void* d_out, int out_size, void* d_ws, size_t ws_size,
                              hipStream_t stream)
{
  const float* x          = (const float*)d_in[0];
  const float* mask       = (const float*)d_in[1];
  const float* w_qkv      = (const float*)d_in[2];
  const float* b_qkv      = (const float*)d_in[3];
  const float* w_proj     = (const float*)d_in[4];
  const float* b_proj     = (const float*)d_in[5];
  const float* bias_table = (const float*)d_in[6];
  const int*   pos        = (const int*)d_in[7];
  float* out = (float*)d_out;

  // ws layout (bf16 elems): biasNN | wqT | wpT | qkv_chunk | ao  (~109 MB peak)
  unsigned short* biasNN = (unsigned short*)d_ws;                   // 1,244,160
  unsigned short* wqT    = biasNN + N_BIAS;                         //   110,592
  unsigned short* wpT    = wqT + N_WQT;                             //    36,864
  unsigned short* qkvws  = wpT + N_WPT;                             // 26,542,080
  unsigned short* ao     = qkvws + (size_t)BWCHUNK * HH * 3 * QKV_STRIDE; // 26,542,080

  const int prep_total = N_WQT + N_WPT + N_BIAS;
  prep_kernel<<<(prep_total + 255) / 256, 256, 0, stream>>>(
      w_qkv, w_proj, bias_table, pos, wqT, wpT, biasNN);

  for (int p = 0; p < NPASS; p++) {
    const int bw0 = p * BWCHUNK;
    qkv_gemm<<<BWCHUNK * 3, 256, 0, stream>>>(x, b_qkv, wqT, qkvws, bw0);
    attn_bwh<<<BWCHUNK * HH, 256, 0, stream>>>(qkvws, mask, biasNN, ao, bw0);
  }
  proj_mfma<<<(B_ * NW * NN) / 64, 256, 0, stream>>>(ao, wpT, b_proj, out);
}

// Round 6
// 513.379 us; speedup vs baseline: 1.5622x; 1.5622x over previous
//
#include <hip/hip_runtime.h>
#include <math.h>

// EarthAttention3D constants
#define B_   96
#define NW   10
#define NN   144
#define CC   192
#define HH   6
#define DH   32
#define SCALE 0.17677669529663687f  // 1/sqrt(32)

#define XP 200   // xs pitch (bf16): 400 B rows
#define PP 152   // Ps pitch: 304 B rows (12-bank row stride -> <=2-way, free)
#define NPASS 3
#define BWCHUNK 320          // 960 / NPASS
#define QKV_STRIDE (NN * DH) // 4608 elems per (h,s) matrix

typedef __attribute__((ext_vector_type(8))) short v8s;            // 8 x bf16
typedef __attribute__((ext_vector_type(4))) unsigned short v4us;  // 4 x bf16
typedef __attribute__((ext_vector_type(4))) float v4f;            // MFMA acc

__device__ __forceinline__ unsigned short f2b(float f) {  // fp32 -> bf16 RNE
  union { float f; unsigned u; } v; v.f = f;
  unsigned r = v.u + 0x7fffu + ((v.u >> 16) & 1u);
  return (unsigned short)(r >> 16);
}
__device__ __forceinline__ float b2f(unsigned short s) {
  union { unsigned u; float f; } v; v.u = ((unsigned)s) << 16;
  return v.f;
}

#define N_WQT (576*192)
#define N_WPT (192*192)
#define N_BIAS (NW*HH*NN*NN)

// ---------------------------------------------------------------------------
// Prep: wqT = w_qkv^T bf16, wpT = w_proj^T bf16, biasNN gathered bf16.
// ---------------------------------------------------------------------------
__global__ __launch_bounds__(256) void prep_kernel(
    const float* __restrict__ w_qkv, const float* __restrict__ w_proj,
    const float* __restrict__ bias_table, const int* __restrict__ pos,
    unsigned short* __restrict__ wqT, unsigned short* __restrict__ wpT,
    unsigned short* __restrict__ biasNN)
{
  int i = blockIdx.x * 256 + threadIdx.x;
  if (i < N_WQT) {
    int n = i / 192, k = i % 192;
    wqT[i] = f2b(w_qkv[k * 576 + n]);
  } else if (i < N_WQT + N_WPT) {
    int j = i - N_WQT;
    int n = j / 192, k = j % 192;
    wpT[j] = f2b(w_proj[k * 192 + n]);
  } else if (i < N_WQT + N_WPT + N_BIAS) {
    int j = i - (N_WQT + N_WPT);
    int m = j % NN, n = (j / NN) % NN, h = (j / (NN * NN)) % HH, w = j / (NN * NN * HH);
    biasNN[j] = f2b(bias_table[(pos[n * NN + m] * NW + w) * HH + h]);
  }
}

// ---------------------------------------------------------------------------
// QKV GEMM: block = (bw, 48-row third). 256 thr / 4 waves, 19.2 KB LDS.
// A-fragments hoisted to registers (reused across all 9 col-strips per wave).
// Output layout: q,k: [n][d];  v: TRANSPOSED [d][n] (packed 8B stores) so the
// attention kernel needs no LDS transpose at all.
// ---------------------------------------------------------------------------
__global__ __launch_bounds__(256, 3) void qkv_gemm(
    const float* __restrict__ x, const float* __restrict__ b_qkv,
    const unsigned short* __restrict__ wqT,
    unsigned short* __restrict__ qkv, int bw0)
{
  __shared__ unsigned short xs[48 * XP];   // 19,200 B
  const int tid  = threadIdx.x;
  const int wave = tid >> 6, lane = tid & 63;
  const int lr = lane & 15, lk8 = (lane >> 4) * 8, quad = lane >> 4;
  const int bwl = blockIdx.x / 3;
  const int rt3 = blockIdx.x % 3;
  const int bw  = bw0 + bwl;

  // stage 48 rows of x as bf16
  const float4* xp4 = (const float4*)(x + ((size_t)bw * NN + rt3 * 48) * CC);
  for (int i = tid; i < 48 * (CC / 4); i += 256) {
    float4 f = xp4[i];
    int r = i / (CC / 4), c = (i % (CC / 4)) * 4;
    unsigned short* d = &xs[r * XP + c];
    d[0] = f2b(f.x); d[1] = f2b(f.y); d[2] = f2b(f.z); d[3] = f2b(f.w);
  }
  __syncthreads();

  // hoist A-fragments: 3 row-tiles x 6 k-steps = 18 v8s (72 VGPRs)
  v8s a[3][6];
  #pragma unroll
  for (int ii = 0; ii < 3; ii++)
    #pragma unroll
    for (int ks = 0; ks < 6; ks++)
      a[ii][ks] = *(const v8s*)&xs[(ii * 16 + lr) * XP + ks * 32 + lk8];

  for (int c = wave; c < 36; c += 4) {      // 9 col-strips per wave
    const int s = c / 12;
    const int h = (c % 12) >> 1;
    const int dhalf = c & 1;
    const unsigned short* wrow = wqT + (size_t)(c * 16 + lr) * CC;
    v8s bf[6];
    #pragma unroll
    for (int ks = 0; ks < 6; ks++) bf[ks] = *(const v8s*)&wrow[ks * 32 + lk8];
    const float bv = b_qkv[c * 16 + lr];
    v4f acc[3];
    #pragma unroll
    for (int ii = 0; ii < 3; ii++) acc[ii] = (v4f){bv, bv, bv, bv};
    #pragma unroll
    for (int ks = 0; ks < 6; ks++)
      #pragma unroll
      for (int ii = 0; ii < 3; ii++)
        acc[ii] = __builtin_amdgcn_mfma_f32_16x16x32_bf16(a[ii][ks], bf[ks], acc[ii], 0, 0, 0);

    if (s == 2) {
      // V: store transposed [d][n], d = c-strip output channel, 4 n packed/8B
      unsigned short* opT = qkv + ((size_t)(bwl * HH + h) * 3 + 2) * QKV_STRIDE
                          + (size_t)(dhalf * 16 + lr) * NN;
      #pragma unroll
      for (int ii = 0; ii < 3; ii++) {
        const int n0 = rt3 * 48 + ii * 16 + quad * 4;
        v4us pk;
        #pragma unroll
        for (int r = 0; r < 4; r++) pk[r] = f2b(acc[ii][r]);
        *(v4us*)&opT[n0] = pk;
      }
    } else {
      unsigned short* op = qkv + ((size_t)(bwl * HH + h) * 3 + s) * QKV_STRIDE + dhalf * 16 + lr;
      #pragma unroll
      for (int ii = 0; ii < 3; ii++)
        #pragma unroll
        for (int r = 0; r < 4; r++) {
          const int n = rt3 * 48 + ii * 16 + quad * 4 + r;
          op[n * DH] = f2b(acc[ii][r]);
        }
    }
  }
}

// ---------------------------------------------------------------------------
// Attention per (b,w,h): 256 thr / 4 waves, 43.8 KB LDS -> 3 blocks/CU.
// Phase B is pure MFMA->LDS (no global gathers). Bias+mask are folded into
// the softmax read where 16-lane row groups give coalesced, batched loads.
// ---------------------------------------------------------------------------
__global__ __launch_bounds__(256, 2) void attn_bwh(
    const unsigned short* __restrict__ qkv, const float* __restrict__ mask,
    const unsigned short* __restrict__ biasNN,
    unsigned short* __restrict__ ao, int bw0)
{
  __shared__ unsigned short Ps[NN * PP];   // 43,776 B

  const int tid  = threadIdx.x;
  const int wave = tid >> 6, lane = tid & 63;
  const int lr = lane & 15, lk8 = (lane >> 4) * 8, quad = lane >> 4;

  const int bwl = blockIdx.x / HH;
  const int h   = blockIdx.x % HH;
  const int bw  = bw0 + bwl;
  const int b   = bw / NW;
  const int w   = bw % NW;

  const unsigned short* qp = qkv + (size_t)(bwl * HH + h) * 3 * QKV_STRIDE;
  const unsigned short* kp = qp + QKV_STRIDE;
  const unsigned short* vT = qp + 2 * QKV_STRIDE;   // [32][144] transposed

  // hoist phase-D V^T fragments NOW: loads complete under the barrier drain
  v8s bv[2][4], bvt[2];
  #pragma unroll
  for (int dh2 = 0; dh2 < 2; dh2++) {
    const unsigned short* vrow = vT + (size_t)(dh2 * 16 + lr) * NN;
    #pragma unroll
    for (int ks = 0; ks < 4; ks++) bv[dh2][ks] = *(const v8s*)&vrow[ks * 32 + lk8];
    bvt[dh2] = *(const v8s*)&vrow[128 + (lk8 & 8)];
  }

  // ---- phase B: S = scale * q k^T -> bf16 in Ps (no global gathers) -------
  v8s aq[9];
  #pragma unroll
  for (int nt = 0; nt < 9; nt++)
    aq[nt] = *(const v8s*)&qp[(nt * 16 + lr) * DH + lk8];

  for (int mt = wave; mt < 9; mt += 4) {
    v8s bk = *(const v8s*)&kp[(mt * 16 + lr) * DH + lk8];
    const int m = mt * 16 + lr;
    #pragma unroll
    for (int nt = 0; nt < 9; nt++) {
      v4f c = {0.f, 0.f, 0.f, 0.f};
      c = __builtin_amdgcn_mfma_f32_16x16x32_bf16(aq[nt], bk, c, 0, 0, 0);
      #pragma unroll
      for (int r = 0; r < 4; r++) {
        const int n = nt * 16 + quad * 4 + r;
        Ps[n * PP + m] = f2b(c[r] * SCALE);
      }
    }
  }
  __syncthreads();

  // ---- softmax + bias + mask: one 16-lane group per row -------------------
  // bias/mask reads are coalesced (16 consecutive elems per group) and
  // batched up-front (18 independent loads in flight per row).
  const unsigned short* bp = biasNN + (size_t)(w * HH + h) * NN * NN;
  const float* mp = mask + (size_t)b * NN * NN;
  for (int rr = 0; rr < 9; rr++) {
    const int row = rr * 16 + wave * 4 + quad;
    unsigned short* prow = &Ps[row * PP];
    const unsigned short* brow = bp + (size_t)row * NN;
    const float* mrow = mp + (size_t)row * NN;
    float bm[9];
    #pragma unroll
    for (int j = 0; j < 9; j++)
      bm[j] = b2f(brow[j * 16 + lr]) + mrow[j * 16 + lr];
    float e[9];
    float mx = -1e30f;
    #pragma unroll
    for (int j = 0; j < 9; j++) {
      e[j] = b2f(prow[j * 16 + lr]) + bm[j];
      mx = fmaxf(mx, e[j]);
    }
    #pragma unroll
    for (int off = 8; off; off >>= 1) mx = fmaxf(mx, __shfl_xor(mx, off, 64));
    float s = 0.f;
    #pragma unroll
    for (int j = 0; j < 9; j++) { e[j] = __expf(e[j] - mx); s += e[j]; }
    #pragma unroll
    for (int off = 8; off; off >>= 1) s += __shfl_xor(s, off, 64);
    const float inv = 1.f / s;
    #pragma unroll
    for (int j = 0; j < 9; j++) prow[j * 16 + lr] = f2b(e[j] * inv);
  }
  __syncthreads();

  // ---- phase D: O = P @ v; V^T fragments already in registers -------------
  const v8s vzero = {};
  for (int nt = wave; nt < 9; nt += 4) {
    v8s ap[4];
    #pragma unroll
    for (int ks = 0; ks < 4; ks++)
      ap[ks] = *(const v8s*)&Ps[(nt * 16 + lr) * PP + ks * 32 + lk8];
    v8s at = *(const v8s*)&Ps[(nt * 16 + lr) * PP + 128 + (lk8 & 8)];
    at = (quad < 2) ? at : vzero;   // k = 144..159 contributes zero
    #pragma unroll
    for (int dh2 = 0; dh2 < 2; dh2++) {
      v4f c = {0.f, 0.f, 0.f, 0.f};
      #pragma unroll
      for (int ks = 0; ks < 4; ks++)
        c = __builtin_amdgcn_mfma_f32_16x16x32_bf16(ap[ks], bv[dh2][ks], c, 0, 0, 0);
      c = __builtin_amdgcn_mfma_f32_16x16x32_bf16(at, bvt[dh2], c, 0, 0, 0);
      #pragma unroll
      for (int r = 0; r < 4; r++) {
        const int n = nt * 16 + quad * 4 + r;
        ao[((size_t)bw * NN + n) * CC + h * DH + dh2 * 16 + lr] = f2b(c[r]);
      }
    }
  }
}

// ---------------------------------------------------------------------------
// Proj: out = ao(bf16) @ w_proj + b_proj. 64 rows/block.
// ---------------------------------------------------------------------------
__global__ __launch_bounds__(256) void proj_mfma(
    const unsigned short* __restrict__ ao,
    const unsigned short* __restrict__ wpT,
    const float* __restrict__ b_proj,
    float* __restrict__ out)
{
  __shared__ unsigned short As[64 * XP];   // 25,600 B
  const int tid  = threadIdx.x;
  const int wave = tid >> 6, lane = tid & 63;
  const int lr = lane & 15, lk8 = (lane >> 4) * 8, quad = lane >> 4;
  const size_t row0 = (size_t)blockIdx.x * 64;

  for (int i = tid; i < 64 * 24; i += 256) {
    const int r = i / 24, c = i % 24;
    *(v8s*)&As[r * XP + c * 8] = *(const v8s*)(ao + (row0 + r) * CC + c * 8);
  }
  __syncthreads();

  v4f acc[12];
  #pragma unroll
  for (int j = 0; j < 12; j++) {
    const float bv = b_proj[j * 16 + lr];
    acc[j] = (v4f){bv, bv, bv, bv};
  }
  #pragma unroll
  for (int ks = 0; ks < 6; ks++) {
    const int k0 = ks * 32;
    v8s a = *(const v8s*)&As[(wave * 16 + lr) * XP + k0 + lk8];
    #pragma unroll
    for (int j = 0; j < 12; j++) {
      v8s bf = *(const v8s*)(wpT + (j * 16 + lr) * CC + k0 + lk8);
      acc[j] = __builtin_amdgcn_mfma_f32_16x16x32_bf16(a, bf, acc[j], 0, 0, 0);
    }
  }
  #pragma unroll
  for (int j = 0; j < 12; j++)
    #pragma unroll
    for (int r = 0; r < 4; r++)
      out[(row0 + wave * 16 + quad * 4 + r) * CC + j * 16 + lr] = acc[j][r];
}

// ---------------------------------------------------------------------------
extern "C" void kernel_launch(void* const* d_in, const int* in_sizes, int n_in,
                              void* d_out, int out_size, void* d_ws, size_t ws_size,
                              hipStream_t stream)
{
  const float* x          = (const float*)d_in[0];
  const float* mask       = (const float*)d_in[1];
  const float* w_qkv      = (const float*)d_in[2];
  const float* b_qkv      = (const float*)d_in[3];
  const float* w_proj     = (const float*)d_in[4];
  const float* b_proj     = (const float*)d_in[5];
  const float* bias_table = (const float*)d_in[6];
  const int*   pos        = (const int*)d_in[7];
  float* out = (float*)d_out;

  // ws layout (bf16 elems): biasNN | wqT | wpT | qkv_chunk | ao  (~109 MB peak)
  unsigned short* biasNN = (unsigned short*)d_ws;                   // 1,244,160
  unsigned short* wqT    = biasNN + N_BIAS;                         //   110,592
  unsigned short* wpT    = wqT + N_WQT;                             //    36,864
  unsigned short* qkvws  = wpT + N_WPT;                             // 26,542,080
  unsigned short* ao     = qkvws + (size_t)BWCHUNK * HH * 3 * QKV_STRIDE; // 26,542,080

  const int prep_total = N_WQT + N_WPT + N_BIAS;
  prep_kernel<<<(prep_total + 255) / 256, 256, 0, stream>>>(
      w_qkv, w_proj, bias_table, pos, wqT, wpT, biasNN);

  for (int p = 0; p < NPASS; p++) {
    const int bw0 = p * BWCHUNK;
    qkv_gemm<<<BWCHUNK * 3, 256, 0, stream>>>(x, b_qkv, wqT, qkvws, bw0);
    attn_bwh<<<BWCHUNK * HH, 256, 0, stream>>>(qkvws, mask, biasNN, ao, bw0);
  }
  proj_mfma<<<(B_ * NW * NN) / 64, 256, 0, stream>>>(ao, wpT, b_proj, out);
}

// Round 8
// 476.109 us; speedup vs baseline: 1.6845x; 1.0783x over previous
//
#include <hip/hip_runtime.h>
#include <math.h>

// EarthAttention3D constants
#define B_   96
#define NW   10
#define NN   144
#define CC   192
#define HH   6
#define DH   32
#define SCALE 0.17677669529663687f  // 1/sqrt(32)

#define XP 200   // xs pitch (bf16): 400 B rows
#define PP 152   // Ps pitch: 304 B rows (12-bank row stride -> <=2-way, free)
#define NPASS 3
#define BWCHUNK 320          // 960 / NPASS
#define QKV_STRIDE (NN * DH) // 4608 elems per (h,s) matrix

typedef __attribute__((ext_vector_type(8))) short v8s;            // 8 x bf16
typedef __attribute__((ext_vector_type(4))) unsigned short v4us;  // 4 x bf16
typedef __attribute__((ext_vector_type(4))) float v4f;            // MFMA acc

__device__ __forceinline__ unsigned short f2b(float f) {  // fp32 -> bf16 RNE
  union { float f; unsigned u; } v; v.f = f;
  unsigned r = v.u + 0x7fffu + ((v.u >> 16) & 1u);
  return (unsigned short)(r >> 16);
}
__device__ __forceinline__ float b2f(unsigned short s) {
  union { unsigned u; float f; } v; v.u = ((unsigned)s) << 16;
  return v.f;
}

#define N_WQT (576*192)
#define N_WPT (192*192)
#define N_BIAS (NW*HH*NN*NN)

// ---------------------------------------------------------------------------
// Prep: wqT = w_qkv^T bf16, wpT = w_proj^T bf16, biasNN gathered bf16.
// ---------------------------------------------------------------------------
__global__ __launch_bounds__(256) void prep_kernel(
    const float* __restrict__ w_qkv, const float* __restrict__ w_proj,
    const float* __restrict__ bias_table, const int* __restrict__ pos,
    unsigned short* __restrict__ wqT, unsigned short* __restrict__ wpT,
    unsigned short* __restrict__ biasNN)
{
  int i = blockIdx.x * 256 + threadIdx.x;
  if (i < N_WQT) {
    int n = i / 192, k = i % 192;
    wqT[i] = f2b(w_qkv[k * 576 + n]);
  } else if (i < N_WQT + N_WPT) {
    int j = i - N_WQT;
    int n = j / 192, k = j % 192;
    wpT[j] = f2b(w_proj[k * 192 + n]);
  } else if (i < N_WQT + N_WPT + N_BIAS) {
    int j = i - (N_WQT + N_WPT);
    int m = j % NN, n = (j / NN) % NN, h = (j / (NN * NN)) % HH, w = j / (NN * NN * HH);
    biasNN[j] = f2b(bias_table[(pos[n * NN + m] * NW + w) * HH + h]);
  }
}

// ---------------------------------------------------------------------------
// QKV GEMM: block = (bw, 48-row third). 256 thr / 4 waves, 19.2 KB LDS.
// A-fragments hoisted to registers (reused across all 9 col-strips per wave).
// Output layout: q,k: [n][d];  v: TRANSPOSED [d][n] (packed 8B stores) so the
// attention kernel needs no LDS transpose at all.
// ---------------------------------------------------------------------------
__global__ __launch_bounds__(256, 3) void qkv_gemm(
    const float* __restrict__ x, const float* __restrict__ b_qkv,
    const unsigned short* __restrict__ wqT,
    unsigned short* __restrict__ qkv, int bw0)
{
  __shared__ unsigned short xs[48 * XP];   // 19,200 B
  const int tid  = threadIdx.x;
  const int wave = tid >> 6, lane = tid & 63;
  const int lr = lane & 15, lk8 = (lane >> 4) * 8, quad = lane >> 4;
  const int bwl = blockIdx.x / 3;
  const int rt3 = blockIdx.x % 3;
  const int bw  = bw0 + bwl;

  // stage 48 rows of x as bf16
  const float4* xp4 = (const float4*)(x + ((size_t)bw * NN + rt3 * 48) * CC);
  for (int i = tid; i < 48 * (CC / 4); i += 256) {
    float4 f = xp4[i];
    int r = i / (CC / 4), c = (i % (CC / 4)) * 4;
    unsigned short* d = &xs[r * XP + c];
    d[0] = f2b(f.x); d[1] = f2b(f.y); d[2] = f2b(f.z); d[3] = f2b(f.w);
  }
  __syncthreads();

  // hoist A-fragments: 3 row-tiles x 6 k-steps = 18 v8s (72 VGPRs)
  v8s a[3][6];
  #pragma unroll
  for (int ii = 0; ii < 3; ii++)
    #pragma unroll
    for (int ks = 0; ks < 6; ks++)
      a[ii][ks] = *(const v8s*)&xs[(ii * 16 + lr) * XP + ks * 32 + lk8];

  for (int c = wave; c < 36; c += 4) {      // 9 col-strips per wave
    const int s = c / 12;
    const int h = (c % 12) >> 1;
    const int dhalf = c & 1;
    const unsigned short* wrow = wqT + (size_t)(c * 16 + lr) * CC;
    v8s bf[6];
    #pragma unroll
    for (int ks = 0; ks < 6; ks++) bf[ks] = *(const v8s*)&wrow[ks * 32 + lk8];
    const float bv = b_qkv[c * 16 + lr];
    v4f acc[3];
    #pragma unroll
    for (int ii = 0; ii < 3; ii++) acc[ii] = (v4f){bv, bv, bv, bv};
    #pragma unroll
    for (int ks = 0; ks < 6; ks++)
      #pragma unroll
      for (int ii = 0; ii < 3; ii++)
        acc[ii] = __builtin_amdgcn_mfma_f32_16x16x32_bf16(a[ii][ks], bf[ks], acc[ii], 0, 0, 0);

    if (s == 2) {
      // V: store transposed [d][n], d = c-strip output channel, 4 n packed/8B
      unsigned short* opT = qkv + ((size_t)(bwl * HH + h) * 3 + 2) * QKV_STRIDE
                          + (size_t)(dhalf * 16 + lr) * NN;
      #pragma unroll
      for (int ii = 0; ii < 3; ii++) {
        const int n0 = rt3 * 48 + ii * 16 + quad * 4;
        v4us pk;
        #pragma unroll
        for (int r = 0; r < 4; r++) pk[r] = f2b(acc[ii][r]);
        *(v4us*)&opT[n0] = pk;
      }
    } else {
      unsigned short* op = qkv + ((size_t)(bwl * HH + h) * 3 + s) * QKV_STRIDE + dhalf * 16 + lr;
      #pragma unroll
      for (int ii = 0; ii < 3; ii++)
        #pragma unroll
        for (int r = 0; r < 4; r++) {
          const int n = rt3 * 48 + ii * 16 + quad * 4 + r;
          op[n * DH] = f2b(acc[ii][r]);
        }
    }
  }
}

// ---------------------------------------------------------------------------
// Attention per (b,w,h): 256 thr / 4 waves, 43.8 KB LDS -> 3 blocks/CU.
// Phase B is pure MFMA->LDS (no global gathers). Bias+mask are folded into
// the softmax read where 16-lane row groups give coalesced, batched loads.
// ---------------------------------------------------------------------------
__global__ __launch_bounds__(256, 2) void attn_bwh(
    const unsigned short* __restrict__ qkv, const float* __restrict__ mask,
    const unsigned short* __restrict__ biasNN,
    unsigned short* __restrict__ ao, int bw0)
{
  __shared__ unsigned short Ps[NN * PP];   // 43,776 B

  const int tid  = threadIdx.x;
  const int wave = tid >> 6, lane = tid & 63;
  const int lr = lane & 15, lk8 = (lane >> 4) * 8, quad = lane >> 4;

  const int bwl = blockIdx.x / HH;
  const int h   = blockIdx.x % HH;
  const int bw  = bw0 + bwl;
  const int b   = bw / NW;
  const int w   = bw % NW;

  const unsigned short* qp = qkv + (size_t)(bwl * HH + h) * 3 * QKV_STRIDE;
  const unsigned short* kp = qp + QKV_STRIDE;
  const unsigned short* vT = qp + 2 * QKV_STRIDE;   // [32][144] transposed

  // hoist phase-D V^T fragments NOW: loads complete under the barrier drain
  v8s bv[2][4], bvt[2];
  #pragma unroll
  for (int dh2 = 0; dh2 < 2; dh2++) {
    const unsigned short* vrow = vT + (size_t)(dh2 * 16 + lr) * NN;
    #pragma unroll
    for (int ks = 0; ks < 4; ks++) bv[dh2][ks] = *(const v8s*)&vrow[ks * 32 + lk8];
    bvt[dh2] = *(const v8s*)&vrow[128 + (lk8 & 8)];
  }

  // ---- phase B: S = scale * q k^T -> bf16 in Ps (no global gathers) -------
  v8s aq[9];
  #pragma unroll
  for (int nt = 0; nt < 9; nt++)
    aq[nt] = *(const v8s*)&qp[(nt * 16 + lr) * DH + lk8];

  for (int mt = wave; mt < 9; mt += 4) {
    v8s bk = *(const v8s*)&kp[(mt * 16 + lr) * DH + lk8];
    const int m = mt * 16 + lr;
    #pragma unroll
    for (int nt = 0; nt < 9; nt++) {
      v4f c = {0.f, 0.f, 0.f, 0.f};
      c = __builtin_amdgcn_mfma_f32_16x16x32_bf16(aq[nt], bk, c, 0, 0, 0);
      #pragma unroll
      for (int r = 0; r < 4; r++) {
        const int n = nt * 16 + quad * 4 + r;
        Ps[n * PP + m] = f2b(c[r] * SCALE);
      }
    }
  }
  __syncthreads();

  // ---- softmax + bias + mask: one 16-lane group per row -------------------
  // bias/mask reads are coalesced (16 consecutive elems per group) and
  // batched up-front (18 independent loads in flight per row).
  const unsigned short* bp = biasNN + (size_t)(w * HH + h) * NN * NN;
  const float* mp = mask + (size_t)b * NN * NN;
  for (int rr = 0; rr < 9; rr++) {
    const int row = rr * 16 + wave * 4 + quad;
    unsigned short* prow = &Ps[row * PP];
    const unsigned short* brow = bp + (size_t)row * NN;
    const float* mrow = mp + (size_t)row * NN;
    float bm[9];
    #pragma unroll
    for (int j = 0; j < 9; j++)
      bm[j] = b2f(brow[j * 16 + lr]) + mrow[j * 16 + lr];
    float e[9];
    float mx = -1e30f;
    #pragma unroll
    for (int j = 0; j < 9; j++) {
      e[j] = b2f(prow[j * 16 + lr]) + bm[j];
      mx = fmaxf(mx, e[j]);
    }
    #pragma unroll
    for (int off = 8; off; off >>= 1) mx = fmaxf(mx, __shfl_xor(mx, off, 64));
    float s = 0.f;
    #pragma unroll
    for (int j = 0; j < 9; j++) { e[j] = __expf(e[j] - mx); s += e[j]; }
    #pragma unroll
    for (int off = 8; off; off >>= 1) s += __shfl_xor(s, off, 64);
    const float inv = 1.f / s;
    #pragma unroll
    for (int j = 0; j < 9; j++) prow[j * 16 + lr] = f2b(e[j] * inv);
  }
  __syncthreads();

  // ---- phase D: O = P @ v; V^T fragments already in registers -------------
  const v8s vzero = {};
  for (int nt = wave; nt < 9; nt += 4) {
    v8s ap[4];
    #pragma unroll
    for (int ks = 0; ks < 4; ks++)
      ap[ks] = *(const v8s*)&Ps[(nt * 16 + lr) * PP + ks * 32 + lk8];
    v8s at = *(const v8s*)&Ps[(nt * 16 + lr) * PP + 128 + (lk8 & 8)];
    at = (quad < 2) ? at : vzero;   // k = 144..159 contributes zero
    #pragma unroll
    for (int dh2 = 0; dh2 < 2; dh2++) {
      v4f c = {0.f, 0.f, 0.f, 0.f};
      #pragma unroll
      for (int ks = 0; ks < 4; ks++)
        c = __builtin_amdgcn_mfma_f32_16x16x32_bf16(ap[ks], bv[dh2][ks], c, 0, 0, 0);
      c = __builtin_amdgcn_mfma_f32_16x16x32_bf16(at, bvt[dh2], c, 0, 0, 0);
      #pragma unroll
      for (int r = 0; r < 4; r++) {
        const int n = nt * 16 + quad * 4 + r;
        ao[((size_t)bw * NN + n) * CC + h * DH + dh2 * 16 + lr] = f2b(c[r]);
      }
    }
  }
}

// ---------------------------------------------------------------------------
// Proj v2: out = ao(bf16) @ w_proj + b_proj. 64 rows/block, NO LDS, NO
// barriers. Wave w owns output cols j in {3w..3w+2}; its 18 wpT fragments
// live in registers for the whole block (wpT traffic /16 vs v1). A-fragments
// read direct from global: per ks a wave covers 16 rows x 64 B contiguous,
// LLC/L1-hot (4 waves share the same 64 rows). Bit-identical arithmetic.
// ---------------------------------------------------------------------------
__global__ __launch_bounds__(256) void proj_mfma(
    const unsigned short* __restrict__ ao,
    const unsigned short* __restrict__ wpT,
    const float* __restrict__ b_proj,
    float* __restrict__ out)
{
  const int tid  = threadIdx.x;
  const int wave = tid >> 6, lane = tid & 63;
  const int lr = lane & 15, lk8 = (lane >> 4) * 8, quad = lane >> 4;
  const size_t row0 = (size_t)blockIdx.x * 64;
  const int j0 = wave * 3;   // 3 j-strips of 16 cols per wave = 48 cols

  // hoist wpT fragments: 3 j x 6 ks = 18 v8s (72 VGPRs), once per block
  v8s bf[3][6];
  #pragma unroll
  for (int jj = 0; jj < 3; jj++)
    #pragma unroll
    for (int ks = 0; ks < 6; ks++)
      bf[jj][ks] = *(const v8s*)(wpT + (size_t)((j0 + jj) * 16 + lr) * CC + ks * 32 + lk8);

  float bvj[3];
  #pragma unroll
  for (int jj = 0; jj < 3; jj++) bvj[jj] = b_proj[(j0 + jj) * 16 + lr];

  #pragma unroll
  for (int rt = 0; rt < 4; rt++) {
    const size_t r0 = row0 + rt * 16;
    v8s a[6];
    #pragma unroll
    for (int ks = 0; ks < 6; ks++)
      a[ks] = *(const v8s*)(ao + (r0 + lr) * CC + ks * 32 + lk8);
    v4f acc[3];
    #pragma unroll
    for (int jj = 0; jj < 3; jj++) acc[jj] = (v4f){bvj[jj], bvj[jj], bvj[jj], bvj[jj]};
    #pragma unroll
    for (int ks = 0; ks < 6; ks++)
      #pragma unroll
      for (int jj = 0; jj < 3; jj++)
        acc[jj] = __builtin_amdgcn_mfma_f32_16x16x32_bf16(a[ks], bf[jj][ks], acc[jj], 0, 0, 0);
    #pragma unroll
    for (int jj = 0; jj < 3; jj++)
      #pragma unroll
      for (int r = 0; r < 4; r++)
        out[(r0 + quad * 4 + r) * CC + (j0 + jj) * 16 + lr] = acc[jj][r];
  }
}

// ---------------------------------------------------------------------------
extern "C" void kernel_launch(void* const* d_in, const int* in_sizes, int n_in,
                              void* d_out, int out_size, void* d_ws, size_t ws_size,
                              hipStream_t stream)
{
  const float* x          = (const float*)d_in[0];
  const float* mask       = (const float*)d_in[1];
  const float* w_qkv      = (const float*)d_in[2];
  const float* b_qkv      = (const float*)d_in[3];
  const float* w_proj     = (const float*)d_in[4];
  const float* b_proj     = (const float*)d_in[5];
  const float* bias_table = (const float*)d_in[6];
  const int*   pos        = (const int*)d_in[7];
  float* out = (float*)d_out;

  // ws layout (bf16 elems): biasNN | wqT | wpT | qkv_chunk | ao  (~109 MB peak)
  unsigned short* biasNN = (unsigned short*)d_ws;                   // 1,244,160
  unsigned short* wqT    = biasNN + N_BIAS;                         //   110,592
  unsigned short* wpT    = wqT + N_WQT;                             //    36,864
  unsigned short* qkvws  = wpT + N_WPT;                             // 26,542,080
  unsigned short* ao     = qkvws + (size_t)BWCHUNK * HH * 3 * QKV_STRIDE; // 26,542,080

  const int prep_total = N_WQT + N_WPT + N_BIAS;
  prep_kernel<<<(prep_total + 255) / 256, 256, 0, stream>>>(
      w_qkv, w_proj, bias_table, pos, wqT, wpT, biasNN);

  for (int p = 0; p < NPASS; p++) {
    const int bw0 = p * BWCHUNK;
    qkv_gemm<<<BWCHUNK * 3, 256, 0, stream>>>(x, b_qkv, wqT, qkvws, bw0);
    attn_bwh<<<BWCHUNK * HH, 256, 0, stream>>>(qkvws, mask, biasNN, ao, bw0);
  }
  proj_mfma<<<(B_ * NW * NN) / 64, 256, 0, stream>>>(ao, wpT, b_proj, out);
}